// Round 4
// baseline (572.939 us; speedup 1.0000x reference)
//
#include <hip/hip_runtime.h>
#include <hip/hip_bf16.h>
#include <math.h>

#define D_MODEL 1024
#define N_HEAD 16
#define HEAD 64
#define SEQ 2048
#define BATCH 4
#define ROWS (BATCH*SEQ)
#define FFD 4096

typedef __bf16 bf16;
typedef __attribute__((ext_vector_type(8))) __bf16 bf16x8;
typedef __attribute__((ext_vector_type(4))) __bf16 bf16x4;
typedef __attribute__((ext_vector_type(4))) float f32x4;
typedef __attribute__((ext_vector_type(4))) short short4v;

static_assert(sizeof(bf16x8) == 16, "bf16x8 must be 16B");

__device__ __forceinline__ void async_copy16(const void* g, void* l) {
  __builtin_amdgcn_global_load_lds((const __attribute__((address_space(1))) void*)g,
                                   (__attribute__((address_space(3))) void*)l, 16, 0, 0);
}

// Opaque LDS read: invisible to the compiler's waitcnt legalizer -> no automatic
// protection; ordering is entirely our asm waits + sched_barrier(0) (rule #18).
__device__ __forceinline__ bf16x8 dsr16(const bf16* p) {
  bf16x8 r;
  const __attribute__((address_space(3))) bf16* lp =
      (const __attribute__((address_space(3))) bf16*)(unsigned int)(size_t)p;
  asm volatile("ds_read_b128 %0, %1" : "=v"(r) : "v"(lp));
  return r;
}

// Raw barrier: the memory legalizer attaches a vmcnt(0) drain to the BUILTIN
// s_barrier when global_load_lds is in flight (the R2/R3 stall: ~900+cyc HBM
// latency exposed EVERY phase). A bare asm s_barrier gets no such drain; the
// "memory" clobber still pins all compiler-visible memory ops across it.
#define BAR() asm volatile("s_barrier" ::: "memory")

__device__ __forceinline__ f32x4 mfma16(bf16x8 a, bf16x8 b, f32x4 c) {
  return __builtin_amdgcn_mfma_f32_16x16x32_bf16(a, b, c, 0, 0, 0);
}

__device__ __forceinline__ f32x4 mfma16k16(bf16x4 a, bf16x4 b, f32x4 c) {
#if __has_builtin(__builtin_amdgcn_mfma_f32_16x16x16_bf16)
  return __builtin_amdgcn_mfma_f32_16x16x16_bf16(a, b, c, 0, 0, 0);
#else
  return __builtin_amdgcn_mfma_f32_16x16x16bf16_1k(__builtin_bit_cast(short4v, a),
                                                   __builtin_bit_cast(short4v, b), c, 0, 0, 0);
#endif
}

__device__ __forceinline__ float fast_exp2(float x) {
#if __has_builtin(__builtin_amdgcn_exp2f)
  return __builtin_amdgcn_exp2f(x);
#else
  float r; asm("v_exp_f32 %0, %1" : "=v"(r) : "v"(x)); return r;
#endif
}

// tanh-form GELU: ~10 VALU ops vs ~40 for libm erff. Max abs dev vs exact ~1e-3,
// attenuated through W2 (~4e-3 on output) — well inside the 0.119 threshold margin.
__device__ __forceinline__ float fast_gelu(float x) {
  const float y = 0.7978845608f * (x + 0.044715f * x * x * x);
  const float e = fast_exp2(y * 2.88539008178f);  // exp(2y)
  return 0.5f * x * (1.f + (1.f - 2.f / (e + 1.f)));
}

// ---------------- weight transpose + cast: in fp32 [R][C] -> out bf16 [C][R] ----------------
__global__ __launch_bounds__(256) void transpose_cast_kernel(const float* __restrict__ in,
                                                             bf16* __restrict__ out,
                                                             int R, int C) {
  __shared__ float ts[32][33];
  const int r0 = blockIdx.y * 32, c0 = blockIdx.x * 32;
  const int t = threadIdx.x, lr = t >> 3, lc = (t & 7) * 4;
  const float4 v = *(const float4*)(in + (size_t)(r0 + lr) * C + c0 + lc);
  ts[lr][lc + 0] = v.x; ts[lr][lc + 1] = v.y; ts[lr][lc + 2] = v.z; ts[lr][lc + 3] = v.w;
  __syncthreads();
  bf16x4 o;
  o[0] = (bf16)ts[lc + 0][lr]; o[1] = (bf16)ts[lc + 1][lr];
  o[2] = (bf16)ts[lc + 2][lr]; o[3] = (bf16)ts[lc + 3][lr];
  *(bf16x4*)(out + (size_t)(c0 + lr) * R + r0 + lc) = o;
}

// Wq/Wk/Wv [H][C][hs] fp32 -> out bf16 [3][N=H*hs][K=C]  (B^T layout for the QKV GEMM)
__global__ __launch_bounds__(256) void qkv_transpose_kernel(const float* __restrict__ Wq,
                                                            const float* __restrict__ Wk,
                                                            const float* __restrict__ Wv,
                                                            bf16* __restrict__ out) {
  __shared__ float ts[32][33];
  const int mat = blockIdx.z / N_HEAD, h = blockIdx.z % N_HEAD;
  const float* W = (mat == 0 ? Wq : mat == 1 ? Wk : Wv) + (size_t)h * D_MODEL * HEAD;
  bf16* o = out + (size_t)mat * D_MODEL * D_MODEL + (size_t)(h * HEAD) * D_MODEL;
  const int c0 = blockIdx.x * 32, s0 = blockIdx.y * 32;
  const int t = threadIdx.x, lr = t >> 3, lc = (t & 7) * 4;
  const float4 v = *(const float4*)(W + (size_t)(c0 + lr) * HEAD + s0 + lc);
  ts[lr][lc + 0] = v.x; ts[lr][lc + 1] = v.y; ts[lr][lc + 2] = v.z; ts[lr][lc + 3] = v.w;
  __syncthreads();
  bf16x4 ov;
  ov[0] = (bf16)ts[lc + 0][lr]; ov[1] = (bf16)ts[lc + 1][lr];
  ov[2] = (bf16)ts[lc + 2][lr]; ov[3] = (bf16)ts[lc + 3][lr];
  *(bf16x4*)(o + (size_t)(s0 + lr) * D_MODEL + c0 + lc) = ov;
}

// ---------------- LayerNorm: fp32 in -> bf16 out, one block per row ----------------
__global__ __launch_bounds__(256) void ln_kernel(const float* __restrict__ x,
                                                 const float* __restrict__ g,
                                                 const float* __restrict__ b,
                                                 bf16* __restrict__ h) {
  const int row = blockIdx.x, t = threadIdx.x;
  const float4 v = *(const float4*)(x + (size_t)row * D_MODEL + t * 4);
  float s = v.x + v.y + v.z + v.w;
  float ss = v.x * v.x + v.y * v.y + v.z * v.z + v.w * v.w;
#pragma unroll
  for (int m = 1; m < 64; m <<= 1) { s += __shfl_xor(s, m); ss += __shfl_xor(ss, m); }
  __shared__ float red[8];
  const int wave = t >> 6, lane = t & 63;
  if (lane == 0) { red[wave] = s; red[4 + wave] = ss; }
  __syncthreads();
  s = red[0] + red[1] + red[2] + red[3];
  ss = red[4] + red[5] + red[6] + red[7];
  const float mu = s * (1.f / D_MODEL);
  const float rstd = rsqrtf(ss * (1.f / D_MODEL) - mu * mu + 1e-5f);
  const float4 gv = *(const float4*)(g + t * 4);
  const float4 bv = *(const float4*)(b + t * 4);
  bf16x4 o;
  o[0] = (bf16)((v.x - mu) * rstd * gv.x + bv.x);
  o[1] = (bf16)((v.y - mu) * rstd * gv.y + bv.y);
  o[2] = (bf16)((v.z - mu) * rstd * gv.z + bv.z);
  o[3] = (bf16)((v.w - mu) * rstd * gv.w + bv.w);
  *(bf16x4*)(h + (size_t)row * D_MODEL + t * 4) = o;
}

// ---------------- pipelined GEMM: BMx256 tile, 8 waves, 4 phases/K-tile, raw-asm sync ----------
// C[M][N] = A[M][K](bf16 rm) x Bt[N][K](bf16 rm). BM in {256,128}, BN=256, BK=64 (2 k-halves).
// LDS: As[buf][khalf][BM][32], Bs[buf][khalf][256][32]; 16B-chunk XOR swizzle phys=log^((row>>1)&3)
// (pre-swizzled global source + swizzled ds_read chunk; gload_lds dests lane-linear — rule #21;
// verified conflict-free: SQ_LDS_BANK_CONFLICT=0 in R2/R3).
// ALL sync in the loop is raw asm: s_barrier (no legalizer drain), counted vmcnt once per
// K-tile (T4), lgkmcnt(0) per phase, sched_barrier(0) to fence MFMA hoisting (rule #18).
// Stage slots (re-verified): P1->A(kt+1,kh1) [last read P3@kt-1? no: other-buf region last read
// at P3/P4 of kt-1, complete by P4@kt-1's barrier]; P2->B(kt+2,kh0) [last read P1@kt];
// P3->A(kt+2,kh0) [last read P2@kt]; P4->B(kt+2,kh1) [last read P3@kt]. vmcnt at P4 leaves
// exactly tile kt+2's 3 k-half groups in flight; all of tile kt+1 resident.
#define STAGE_A(kt2, h)                                                          \
  do {                                                                           \
    const int off_ = (kt2) * 64 + (h) * 32;                                      \
    bf16* d_ = aDst0 + (((kt2) & 1) * 2 + (h)) * AHALF;                          \
    async_copy16(aSrc0 + off_, d_);                                              \
    if (ASTEPS == 2) async_copy16(aSrc1 + off_, d_ + 4096);                      \
  } while (0)

#define STAGE_B(kt2, h)                                                          \
  do {                                                                           \
    const int off_ = (kt2) * 64 + (h) * 32;                                      \
    bf16* d_ = bDst0 + (((kt2) & 1) * 2 + (h)) * 8192;                           \
    async_copy16(bSrc0 + off_, d_);                                              \
    async_copy16(bSrc1 + off_, d_ + 4096);                                       \
  } while (0)

template <int EPI, int BM>
__device__ __forceinline__ void gemm_body(const bf16* A, const bf16* Bt, int K,
                                          void* outp, const float* bias,
                                          const float* resid, bf16* q_out,
                                          bf16* k_out, bf16* vt_out, int N) {
  constexpr int ASTEPS = BM / 128;  // global_load_lds per thread per A k-half
  constexpr int MPW = BM / 2;       // rows per wave (2 waves along M, 4 along N)
  constexpr int MREP = MPW / 16;
  constexpr int MH = MREP / 2;      // mi-half size (phase granularity)
  constexpr int AHALF = BM * 32;    // elems per A k-half
  __shared__ bf16 As[2 * 2 * BM * 32];
  __shared__ bf16 Bs[2 * 2 * 256 * 32];
  const int t = threadIdx.x, wave = t >> 6, lane = t & 63;
  const int l15 = lane & 15, l4 = lane >> 4;
  // XCD-chunked swizzle, bm-FASTEST within a chunk: the ~32 concurrently-resident blocks of
  // an XCD share ONE 512KB-2MB B-strip (L2-resident) instead of thrashing the full B panel.
  const int lin = ((int)blockIdx.x & 7) * ((int)gridDim.x >> 3) + ((int)blockIdx.x >> 3);
  const int nbn = N >> 8;
  const int nbm = (int)gridDim.x / nbn;
  const int bm = lin % nbm, bn = lin / nbm;
  const int nk = K >> 6;

  // staging: thread t covers row r0 (+128 for step 1), pre-swizzled source chunk sc
  const int sc = (lane & 3) ^ ((lane >> 3) & 3);
  const int r0 = wave * 16 + (lane >> 2);
  const bf16* aSrc0 = A + (size_t)(bm * BM + r0) * K + sc * 8;
  const bf16* aSrc1 = (ASTEPS == 2) ? (A + (size_t)(bm * BM + 128 + r0) * K + sc * 8) : aSrc0;
  const bf16* bSrc0 = Bt + (size_t)(bn * 256 + r0) * K + sc * 8;
  const bf16* bSrc1 = Bt + (size_t)(bn * 256 + 128 + r0) * K + sc * 8;
  bf16* aDst0 = As + wave * 512;  // wave-uniform base; HW adds lane*16B
  bf16* bDst0 = Bs + wave * 512;

  const int wm = wave >> 2, wn = wave & 3;
  const int rw = wm * MPW, cw = wn * 64;
  // phys chunk for fragment reads: frag row base %16 -> (row>>1)&3 == (l15>>1)&3
  const int pc = (l4 ^ ((l15 >> 1) & 3)) * 8;

  f32x4 acc[MREP][4];
#pragma unroll
  for (int mi = 0; mi < MREP; mi++)
#pragma unroll
    for (int ni = 0; ni < 4; ni++) { f32x4 z = {0.f, 0.f, 0.f, 0.f}; acc[mi][ni] = z; }

  // prologue: tile0 complete + tile1 {B.kh0, A.kh0, B.kh1}; A(1,kh1) staged at kt=0 P1.
  STAGE_A(0, 0); STAGE_B(0, 0); STAGE_A(0, 1); STAGE_B(0, 1);
  STAGE_B(1, 0); STAGE_A(1, 0); STAGE_B(1, 1);
  if constexpr (ASTEPS == 2) asm volatile("s_waitcnt vmcnt(6)" ::: "memory");
  else                       asm volatile("s_waitcnt vmcnt(5)" ::: "memory");
  BAR();
  __builtin_amdgcn_sched_barrier(0);

  for (int kt = 0; kt < nk; kt++) {
    const bf16* Ab = As + (kt & 1) * (2 * AHALF);
    const bf16* Bb = Bs + (kt & 1) * 16384;
    bf16x8 aF[MH], bF[4];

    // ---- P1 (kh0, mihalf0)
    if (kt + 1 < nk) STAGE_A(kt + 1, 1);
#pragma unroll
    for (int mi = 0; mi < MH; mi++) aF[mi] = dsr16(Ab + (rw + mi * 16 + l15) * 32 + pc);
#pragma unroll
    for (int ni = 0; ni < 4; ni++) bF[ni] = dsr16(Bb + (cw + ni * 16 + l15) * 32 + pc);
    asm volatile("s_waitcnt lgkmcnt(0)" ::: "memory");
    BAR();
    __builtin_amdgcn_sched_barrier(0);
    __builtin_amdgcn_s_setprio(1);
#pragma unroll
    for (int mi = 0; mi < MH; mi++)
#pragma unroll
      for (int ni = 0; ni < 4; ni++) acc[mi][ni] = mfma16(aF[mi], bF[ni], acc[mi][ni]);
    __builtin_amdgcn_s_setprio(0);

    // ---- P2 (kh0, mihalf1): bF reused from registers
    if (kt + 2 < nk) STAGE_B(kt + 2, 0);
#pragma unroll
    for (int mi = 0; mi < MH; mi++) aF[mi] = dsr16(Ab + (rw + (MH + mi) * 16 + l15) * 32 + pc);
    asm volatile("s_waitcnt lgkmcnt(0)" ::: "memory");
    BAR();
    __builtin_amdgcn_sched_barrier(0);
    __builtin_amdgcn_s_setprio(1);
#pragma unroll
    for (int mi = 0; mi < MH; mi++)
#pragma unroll
      for (int ni = 0; ni < 4; ni++) acc[MH + mi][ni] = mfma16(aF[mi], bF[ni], acc[MH + mi][ni]);
    __builtin_amdgcn_s_setprio(0);

    // ---- P3 (kh1, mihalf0)
    if (kt + 2 < nk) STAGE_A(kt + 2, 0);
#pragma unroll
    for (int mi = 0; mi < MH; mi++) aF[mi] = dsr16(Ab + AHALF + (rw + mi * 16 + l15) * 32 + pc);
#pragma unroll
    for (int ni = 0; ni < 4; ni++) bF[ni] = dsr16(Bb + 8192 + (cw + ni * 16 + l15) * 32 + pc);
    asm volatile("s_waitcnt lgkmcnt(0)" ::: "memory");
    BAR();
    __builtin_amdgcn_sched_barrier(0);
    __builtin_amdgcn_s_setprio(1);
#pragma unroll
    for (int mi = 0; mi < MH; mi++)
#pragma unroll
      for (int ni = 0; ni < 4; ni++) acc[mi][ni] = mfma16(aF[mi], bF[ni], acc[mi][ni]);
    __builtin_amdgcn_s_setprio(0);

    // ---- P4 (kh1, mihalf1): single counted vmcnt per K-tile
    if (kt + 2 < nk) STAGE_B(kt + 2, 1);
#pragma unroll
    for (int mi = 0; mi < MH; mi++) aF[mi] = dsr16(Ab + AHALF + (rw + (MH + mi) * 16 + l15) * 32 + pc);
    if (kt + 2 < nk) {
      if constexpr (ASTEPS == 2) asm volatile("s_waitcnt vmcnt(6)" ::: "memory");
      else                       asm volatile("s_waitcnt vmcnt(5)" ::: "memory");
    } else {
      asm volatile("s_waitcnt vmcnt(0)" ::: "memory");
    }
    asm volatile("s_waitcnt lgkmcnt(0)" ::: "memory");
    BAR();
    __builtin_amdgcn_sched_barrier(0);
    __builtin_amdgcn_s_setprio(1);
#pragma unroll
    for (int mi = 0; mi < MH; mi++)
#pragma unroll
      for (int ni = 0; ni < 4; ni++) acc[MH + mi][ni] = mfma16(aF[mi], bF[ni], acc[MH + mi][ni]);
    __builtin_amdgcn_s_setprio(0);
  }

  // C/D layout (16x16, m89): col = lane&15, row = (lane>>4)*4 + e
#pragma unroll
  for (int mi = 0; mi < MREP; mi++) {
#pragma unroll
    for (int ni = 0; ni < 4; ni++) {
      const int n = bn * 256 + cw + ni * 16 + l15;
#pragma unroll
      for (int e = 0; e < 4; e++) {
        const int m = bm * BM + rw + mi * 16 + l4 * 4 + e;
        float val = acc[mi][ni][e];
        if constexpr (EPI == 0) {
          const int b = m >> 11, tt = m & 2047;
          if (n < D_MODEL) {
            const int hh = n >> 6, sgl = n & 63;
            q_out[(size_t)((b * N_HEAD + hh) * SEQ + tt) * HEAD + sgl] = (bf16)val;
          } else if (n < 2 * D_MODEL) {
            const int n2 = n - D_MODEL, hh = n2 >> 6, sgl = n2 & 63;
            k_out[(size_t)((b * N_HEAD + hh) * SEQ + tt) * HEAD + sgl] = (bf16)val;
          } else {
            const int n2 = n - 2 * D_MODEL, hh = n2 >> 6, sgl = n2 & 63;
            vt_out[(size_t)((b * N_HEAD + hh) * HEAD + sgl) * SEQ + tt] = (bf16)val;
          }
        } else if constexpr (EPI == 1) {
          ((float*)outp)[(size_t)m * N + n] = val + bias[n] + resid[(size_t)m * N + n];
        } else if constexpr (EPI == 2) {
          ((bf16*)outp)[(size_t)m * N + n] = (bf16)fast_gelu(val + bias[n]);
        } else {
          ((float*)outp)[(size_t)m * N + n] = val + bias[n] + resid[(size_t)m * N + n];
        }
      }
    }
  }
}

#undef STAGE_A
#undef STAGE_B

// plain (non-template) kernel wrappers: no template syntax at launch sites
__global__ __launch_bounds__(512, 2) void gemm_qkv_kernel(const bf16* __restrict__ A,
                                                          const bf16* __restrict__ Bt,
                                                          bf16* __restrict__ q_out,
                                                          bf16* __restrict__ k_out,
                                                          bf16* __restrict__ vt_out) {
  gemm_body<0, 256>(A, Bt, D_MODEL, nullptr, nullptr, nullptr, q_out, k_out, vt_out, 3 * D_MODEL);
}

__global__ __launch_bounds__(512, 2) void gemm_proj_kernel(const bf16* __restrict__ A,
                                                           const bf16* __restrict__ Bt,
                                                           float* __restrict__ outp,
                                                           const float* __restrict__ bias,
                                                           const float* __restrict__ resid) {
  gemm_body<1, 128>(A, Bt, D_MODEL, outp, bias, resid, nullptr, nullptr, nullptr, D_MODEL);
}

__global__ __launch_bounds__(512, 2) void gemm_ff1_kernel(const bf16* __restrict__ A,
                                                          const bf16* __restrict__ Bt,
                                                          bf16* __restrict__ outp,
                                                          const float* __restrict__ bias) {
  gemm_body<2, 256>(A, Bt, D_MODEL, outp, bias, nullptr, nullptr, nullptr, nullptr, FFD);
}

__global__ __launch_bounds__(512, 2) void gemm_ff2_kernel(const bf16* __restrict__ A,
                                                          const bf16* __restrict__ Bt,
                                                          float* __restrict__ outp,
                                                          const float* __restrict__ bias,
                                                          const float* __restrict__ resid) {
  gemm_body<3, 128>(A, Bt, FFD, outp, bias, resid, nullptr, nullptr, nullptr, D_MODEL);
}

// ---------------- attention: S^T trick + XOR-swizzled LDS staging (verified R3) ----------------
__global__ __launch_bounds__(256, 2) void attn_kernel(const bf16* __restrict__ q,
                                                      const bf16* __restrict__ k,
                                                      const bf16* __restrict__ vt,
                                                      bf16* __restrict__ att) {
  __shared__ bf16 Ks[64 * 64];
  __shared__ bf16 Vs[64 * 64];
  const int t = threadIdx.x, wave = t >> 6, lane = t & 63;
  const int l15 = lane & 15, l4 = lane >> 4;
  const int bh = blockIdx.x & 63, qblk = blockIdx.x >> 6;
  const bf16* qb = q + (size_t)bh * SEQ * HEAD;
  const bf16* kb = k + (size_t)bh * SEQ * HEAD;
  const bf16* vb = vt + (size_t)bh * HEAD * SEQ;
  const int qrow = qblk * 256 + wave * 64;

  const int tr = t >> 3, tc = t & 7, sw = tc ^ (tr & 7);
  const bf16* ksrc0 = kb + (size_t)tr * HEAD + sw * 8;
  const bf16* ksrc1 = kb + (size_t)(tr + 32) * HEAD + sw * 8;
  const bf16* vsrc0 = vb + (size_t)tr * SEQ + sw * 8;
  const bf16* vsrc1 = vb + (size_t)(tr + 32) * SEQ + sw * 8;
  bf16* kd0 = Ks + t * 8; bf16* kd1 = Ks + t * 8 + 2048;
  bf16* vd0 = Vs + t * 8; bf16* vd1 = Vs + t * 8 + 2048;

  const float qscale = 0.125f * 1.44269504088896340736f;
  bf16x8 qf[4][2];
#pragma unroll
  for (int qs = 0; qs < 4; qs++)
#pragma unroll
    for (int h = 0; h < 2; h++) {
      const bf16x8 raw = *(const bf16x8*)(qb + (size_t)(qrow + qs * 16 + l15) * HEAD + h * 32 + l4 * 8);
      bf16x8 sc;
#pragma unroll
      for (int e = 0; e < 8; e++) sc[e] = (bf16)((float)raw[e] * qscale);
      qf[qs][h] = sc;
    }

  f32x4 o[4][4];
  float lsum[4] = {0.f, 0.f, 0.f, 0.f};
#pragma unroll
  for (int qs = 0; qs < 4; qs++)
#pragma unroll
    for (int dm = 0; dm < 4; dm++) { f32x4 z = {0.f, 0.f, 0.f, 0.f}; o[qs][dm] = z; }

  const int rsw = l15 & 7;

  for (int u0 = 0; u0 < SEQ; u0 += 64) {
    __syncthreads();
    async_copy16(ksrc0 + (size_t)u0 * HEAD, kd0);
    async_copy16(ksrc1 + (size_t)u0 * HEAD, kd1);
    async_copy16(vsrc0 + u0, vd0);
    async_copy16(vsrc1 + u0, vd1);
    __syncthreads();

    bf16x8 kf[4][2];
#pragma unroll
    for (int n = 0; n < 4; n++)
#pragma unroll
      for (int h = 0; h < 2; h++)
        kf[n][h] = *(const bf16x8*)(Ks + (n * 16 + l15) * 64 + (((h << 2) | l4) ^ rsw) * 8);
    bf16x4 vf[4][4];
#pragma unroll
    for (int dm = 0; dm < 4; dm++)
#pragma unroll
      for (int n = 0; n < 4; n++)
        vf[dm][n] = *(const bf16x4*)(Vs + (dm * 16 + l15) * 64 + ((((n << 1) | (l4 >> 1)) ^ rsw) * 8) + (l4 & 1) * 4);

#pragma unroll
    for (int qs = 0; qs < 4; qs++) {
      f32x4 s[4];
#pragma unroll
      for (int n = 0; n < 4; n++) {
        f32x4 c = {0.f, 0.f, 0.f, 0.f};
        c = mfma16(kf[n][0], qf[qs][0], c);
        c = mfma16(kf[n][1], qf[qs][1], c);
        s[n] = c;
      }
      if (u0 == qrow) {
#pragma unroll
        for (int r = 0; r < 4; r++)
          s[qs][r] = (l15 == l4 * 4 + r) ? 0.f : s[qs][r];
      }
      bf16x4 pf[4];
      float ls = 0.f;
#pragma unroll
      for (int n = 0; n < 4; n++) {
        f32x4 pv;
#pragma unroll
        for (int r = 0; r < 4; r++) { pv[r] = fast_exp2(s[n][r]); ls += pv[r]; }
        bf16x4 pb;
#pragma unroll
        for (int r = 0; r < 4; r++) pb[r] = (bf16)pv[r];
        pf[n] = pb;
      }
      lsum[qs] += ls;
#pragma unroll
      for (int dm = 0; dm < 4; dm++) {
        f32x4 acc = o[qs][dm];
#pragma unroll
        for (int n = 0; n < 4; n++) acc = mfma16k16(vf[dm][n], pf[n], acc);
        o[qs][dm] = acc;
      }
    }
  }

#pragma unroll
  for (int qs = 0; qs < 4; qs++) {
    float l = lsum[qs];
    l += __shfl_xor(l, 16);
    l += __shfl_xor(l, 32);
    lsum[qs] = l;
  }
  const int b = bh >> 4, hh = bh & 15;
#pragma unroll
  for (int qs = 0; qs < 4; qs++) {
    const float linv = 1.0f / lsum[qs];
#pragma unroll
    for (int dm = 0; dm < 4; dm++) {
      bf16x4 ov;
#pragma unroll
      for (int r = 0; r < 4; r++) ov[r] = (bf16)(o[qs][dm][r] * linv);
      *(bf16x4*)(att + (size_t)(b * SEQ + qrow + qs * 16 + l15) * D_MODEL + hh * HEAD + dm * 16 + l4 * 4) = ov;
    }
  }
}

extern "C" void kernel_launch(void* const* d_in, const int* in_sizes, int n_in,
                              void* d_out, int out_size, void* d_ws, size_t ws_size,
                              hipStream_t stream) {
  const float* x   = (const float*)d_in[0];
  const float* Wq  = (const float*)d_in[1];
  const float* Wk  = (const float*)d_in[2];
  const float* Wv  = (const float*)d_in[3];
  const float* Wo  = (const float*)d_in[4];
  const float* bo  = (const float*)d_in[5];
  const float* W1  = (const float*)d_in[6];
  const float* b1  = (const float*)d_in[7];
  const float* W2  = (const float*)d_in[8];
  const float* b2  = (const float*)d_in[9];
  const float* g1  = (const float*)d_in[10];
  const float* be1 = (const float*)d_in[11];
  const float* g2  = (const float*)d_in[12];
  const float* be2 = (const float*)d_in[13];
  float* out = (float*)d_out;

  bf16* Wqkv_t = (bf16*)d_ws;                                  // [3][1024][1024]
  bf16* Wo_t   = Wqkv_t + (size_t)3 * D_MODEL * D_MODEL;       // [1024][1024]
  bf16* W1_t   = Wo_t + (size_t)D_MODEL * D_MODEL;             // [4096][1024]
  bf16* W2_t   = W1_t + (size_t)FFD * D_MODEL;                 // [1024][4096]
  bf16* hbuf   = W2_t + (size_t)D_MODEL * FFD;                 // [8192][1024] (h, later h2)
  float* x1    = (float*)(hbuf + (size_t)ROWS * D_MODEL);      // [8192][1024] fp32
  bf16* big    = (bf16*)(x1 + (size_t)ROWS * D_MODEL);         // qkv (50MB) then ff (64MB)
  bf16* qbuf   = big;
  bf16* kbuf   = qbuf + (size_t)ROWS * D_MODEL;
  bf16* vtbuf  = kbuf + (size_t)ROWS * D_MODEL;
  bf16* ffbuf  = big;                                          // reuse after attention
  bf16* attb   = big + (size_t)ROWS * FFD;                     // [8192][1024]

  qkv_transpose_kernel<<<dim3(D_MODEL / 32, HEAD / 32, 3 * N_HEAD), 256, 0, stream>>>(Wq, Wk, Wv, Wqkv_t);
  transpose_cast_kernel<<<dim3(D_MODEL / 32, D_MODEL / 32), 256, 0, stream>>>(Wo, Wo_t, D_MODEL, D_MODEL);
  transpose_cast_kernel<<<dim3(FFD / 32, D_MODEL / 32), 256, 0, stream>>>(W1, W1_t, D_MODEL, FFD);
  transpose_cast_kernel<<<dim3(D_MODEL / 32, FFD / 32), 256, 0, stream>>>(W2, W2_t, FFD, D_MODEL);
  ln_kernel<<<ROWS, 256, 0, stream>>>(x, g1, be1, hbuf);
  // grids: (N/256)*(M/BM) blocks, 1D, all %8==0 for the XCD swizzle
  gemm_qkv_kernel<<<dim3((3 * D_MODEL / 256) * (ROWS / 256)), 512, 0, stream>>>(
      hbuf, Wqkv_t, qbuf, kbuf, vtbuf);
  attn_kernel<<<64 * (SEQ / 256), 256, 0, stream>>>(qbuf, kbuf, vtbuf, attb);
  gemm_proj_kernel<<<dim3((D_MODEL / 256) * (ROWS / 128)), 512, 0, stream>>>(
      attb, Wo_t, x1, bo, x);
  ln_kernel<<<ROWS, 256, 0, stream>>>(x1, g2, be2, hbuf);
  gemm_ff1_kernel<<<dim3((FFD / 256) * (ROWS / 256)), 512, 0, stream>>>(
      hbuf, W1_t, ffbuf, b1);
  gemm_ff2_kernel<<<dim3((D_MODEL / 256) * (ROWS / 128)), 512, 0, stream>>>(
      ffbuf, W2_t, out, b2, x1);
}

// Round 5
// 559.914 us; speedup vs baseline: 1.0233x; 1.0233x over previous
//
#include <hip/hip_runtime.h>
#include <hip/hip_bf16.h>
#include <math.h>

#define D_MODEL 1024
#define N_HEAD 16
#define HEAD 64
#define SEQ 2048
#define BATCH 4
#define ROWS (BATCH*SEQ)
#define FFD 4096

typedef __bf16 bf16;
typedef __attribute__((ext_vector_type(8))) __bf16 bf16x8;
typedef __attribute__((ext_vector_type(4))) __bf16 bf16x4;
typedef __attribute__((ext_vector_type(4))) float f32x4;
typedef __attribute__((ext_vector_type(4))) short short4v;

static_assert(sizeof(bf16x8) == 16, "bf16x8 must be 16B");

__device__ __forceinline__ void async_copy16(const void* g, void* l) {
  __builtin_amdgcn_global_load_lds((const __attribute__((address_space(1))) void*)g,
                                   (__attribute__((address_space(3))) void*)l, 16, 0, 0);
}

// Opaque LDS read: invisible to the compiler's waitcnt legalizer -> no automatic
// protection; ordering is entirely our asm waits + sched_barrier(0) (rule #18).
__device__ __forceinline__ bf16x8 dsr16(const bf16* p) {
  bf16x8 r;
  const __attribute__((address_space(3))) bf16* lp =
      (const __attribute__((address_space(3))) bf16*)(unsigned int)(size_t)p;
  asm volatile("ds_read_b128 %0, %1" : "=v"(r) : "v"(lp));
  return r;
}

// Raw barrier: no legalizer-attached drains; "memory" clobber pins compiler-visible
// memory ops; volatile-asm mutual order pins it against dsr16/waitcnt asm.
#define BAR() asm volatile("s_barrier" ::: "memory")

__device__ __forceinline__ f32x4 mfma16(bf16x8 a, bf16x8 b, f32x4 c) {
  return __builtin_amdgcn_mfma_f32_16x16x32_bf16(a, b, c, 0, 0, 0);
}

__device__ __forceinline__ f32x4 mfma16k16(bf16x4 a, bf16x4 b, f32x4 c) {
#if __has_builtin(__builtin_amdgcn_mfma_f32_16x16x16_bf16)
  return __builtin_amdgcn_mfma_f32_16x16x16_bf16(a, b, c, 0, 0, 0);
#else
  return __builtin_amdgcn_mfma_f32_16x16x16bf16_1k(__builtin_bit_cast(short4v, a),
                                                   __builtin_bit_cast(short4v, b), c, 0, 0, 0);
#endif
}

__device__ __forceinline__ float fast_exp2(float x) {
#if __has_builtin(__builtin_amdgcn_exp2f)
  return __builtin_amdgcn_exp2f(x);
#else
  float r; asm("v_exp_f32 %0, %1" : "=v"(r) : "v"(x)); return r;
#endif
}

// tanh-form GELU: ~10 VALU ops vs ~40 for libm erff. Max abs dev vs exact ~1e-3,
// attenuated through W2 (~4e-3 on output) — well inside the 0.119 threshold margin.
__device__ __forceinline__ float fast_gelu(float x) {
  const float y = 0.7978845608f * (x + 0.044715f * x * x * x);
  const float e = fast_exp2(y * 2.88539008178f);  // exp(2y)
  return 0.5f * x * (1.f + (1.f - 2.f / (e + 1.f)));
}

// ---------------- weight transpose + cast: in fp32 [R][C] -> out bf16 [C][R] ----------------
__global__ __launch_bounds__(256) void transpose_cast_kernel(const float* __restrict__ in,
                                                             bf16* __restrict__ out,
                                                             int R, int C) {
  __shared__ float ts[32][33];
  const int r0 = blockIdx.y * 32, c0 = blockIdx.x * 32;
  const int t = threadIdx.x, lr = t >> 3, lc = (t & 7) * 4;
  const float4 v = *(const float4*)(in + (size_t)(r0 + lr) * C + c0 + lc);
  ts[lr][lc + 0] = v.x; ts[lr][lc + 1] = v.y; ts[lr][lc + 2] = v.z; ts[lr][lc + 3] = v.w;
  __syncthreads();
  bf16x4 o;
  o[0] = (bf16)ts[lc + 0][lr]; o[1] = (bf16)ts[lc + 1][lr];
  o[2] = (bf16)ts[lc + 2][lr]; o[3] = (bf16)ts[lc + 3][lr];
  *(bf16x4*)(out + (size_t)(c0 + lr) * R + r0 + lc) = o;
}

// Wq/Wk/Wv [H][C][hs] fp32 -> out bf16 [3][N=H*hs][K=C]  (B^T layout for the QKV GEMM)
__global__ __launch_bounds__(256) void qkv_transpose_kernel(const float* __restrict__ Wq,
                                                            const float* __restrict__ Wk,
                                                            const float* __restrict__ Wv,
                                                            bf16* __restrict__ out) {
  __shared__ float ts[32][33];
  const int mat = blockIdx.z / N_HEAD, h = blockIdx.z % N_HEAD;
  const float* W = (mat == 0 ? Wq : mat == 1 ? Wk : Wv) + (size_t)h * D_MODEL * HEAD;
  bf16* o = out + (size_t)mat * D_MODEL * D_MODEL + (size_t)(h * HEAD) * D_MODEL;
  const int c0 = blockIdx.x * 32, s0 = blockIdx.y * 32;
  const int t = threadIdx.x, lr = t >> 3, lc = (t & 7) * 4;
  const float4 v = *(const float4*)(W + (size_t)(c0 + lr) * HEAD + s0 + lc);
  ts[lr][lc + 0] = v.x; ts[lr][lc + 1] = v.y; ts[lr][lc + 2] = v.z; ts[lr][lc + 3] = v.w;
  __syncthreads();
  bf16x4 ov;
  ov[0] = (bf16)ts[lc + 0][lr]; ov[1] = (bf16)ts[lc + 1][lr];
  ov[2] = (bf16)ts[lc + 2][lr]; ov[3] = (bf16)ts[lc + 3][lr];
  *(bf16x4*)(o + (size_t)(s0 + lr) * D_MODEL + c0 + lc) = ov;
}

// ---------------- LayerNorm: fp32 in -> bf16 out, one block per row ----------------
__global__ __launch_bounds__(256) void ln_kernel(const float* __restrict__ x,
                                                 const float* __restrict__ g,
                                                 const float* __restrict__ b,
                                                 bf16* __restrict__ h) {
  const int row = blockIdx.x, t = threadIdx.x;
  const float4 v = *(const float4*)(x + (size_t)row * D_MODEL + t * 4);
  float s = v.x + v.y + v.z + v.w;
  float ss = v.x * v.x + v.y * v.y + v.z * v.z + v.w * v.w;
#pragma unroll
  for (int m = 1; m < 64; m <<= 1) { s += __shfl_xor(s, m); ss += __shfl_xor(ss, m); }
  __shared__ float red[8];
  const int wave = t >> 6, lane = t & 63;
  if (lane == 0) { red[wave] = s; red[4 + wave] = ss; }
  __syncthreads();
  s = red[0] + red[1] + red[2] + red[3];
  ss = red[4] + red[5] + red[6] + red[7];
  const float mu = s * (1.f / D_MODEL);
  const float rstd = rsqrtf(ss * (1.f / D_MODEL) - mu * mu + 1e-5f);
  const float4 gv = *(const float4*)(g + t * 4);
  const float4 bv = *(const float4*)(b + t * 4);
  bf16x4 o;
  o[0] = (bf16)((v.x - mu) * rstd * gv.x + bv.x);
  o[1] = (bf16)((v.y - mu) * rstd * gv.y + bv.y);
  o[2] = (bf16)((v.z - mu) * rstd * gv.z + bv.z);
  o[3] = (bf16)((v.w - mu) * rstd * gv.w + bv.w);
  *(bf16x4*)(h + (size_t)row * D_MODEL + t * 4) = o;
}

// ---------------- pipelined GEMM: 128x128 tile, 4 waves, 3-region rotating LDS ----------------
// C[M][N] = A[M][K](bf16 rm) x Bt[N][K](bf16 rm). Phase = one k-half (K=32).
// LDS: As/Bs = 3 regions x [128 rows][32] each (48 KB total -> 3 blocks/CU, 12 waves: the TLP
// that R2-R4's 1-block/CU lockstep lacked). Region for k-half s = s%3.
// Phase s: { stage G(s+2) into region (s+2)%3 [4 gload_lds/thread]; 8 asm ds_reads of region s%3;
//            vmcnt(4) [leaves only G(s+2) -> G(s+1) resident, 2-phase slack]; lgkmcnt(0);
//            s_barrier; sched_barrier(0); setprio1; 16 MFMA; setprio0 }.
// Overwrite safety by rotation: region (s+2)%3 was last read at phase s-1, whose reads drained
// (lgkm0) before that phase's barrier; the stage issues after it. 16B-chunk XOR swizzle
// phys=log^((row>>1)&3): pre-swizzled global source + swizzled ds_read chunk, lane-linear
// gload_lds dests (rule #21; SQ_LDS_BANK_CONFLICT=0 verified R2-R4).
#define STG(soff, rg)                                                            \
  do {                                                                           \
    const int o_ = (soff) * 32;                                                  \
    bf16* ad_ = aDst + (rg) * 4096;                                              \
    bf16* bd_ = bDst + (rg) * 4096;                                              \
    async_copy16(aSrc0 + o_, ad_);                                               \
    async_copy16(aSrc1 + o_, ad_ + 2048);                                        \
    async_copy16(bSrc0 + o_, bd_);                                               \
    async_copy16(bSrc1 + o_, bd_ + 2048);                                        \
  } while (0)

template <int EPI>
__device__ __forceinline__ void gemm_body(const bf16* A, const bf16* Bt, int K,
                                          void* outp, const float* bias,
                                          const float* resid, bf16* q_out,
                                          bf16* k_out, bf16* vt_out, int N) {
  __shared__ __align__(16) bf16 As[3 * 128 * 32];
  __shared__ __align__(16) bf16 Bs[3 * 128 * 32];
  const int t = threadIdx.x, wave = t >> 6, lane = t & 63;
  const int l15 = lane & 15, l4 = lane >> 4;
  // bijective XCD-chunked swizzle (all grids %8==0), bm-fastest within a chunk
  const int lin = ((int)blockIdx.x & 7) * ((int)gridDim.x >> 3) + ((int)blockIdx.x >> 3);
  const int nbn = N >> 7;
  const int nbm = (int)gridDim.x / nbn;
  const int bm = lin % nbm, bn = lin / nbm;
  const int ns = K >> 5;  // k-half phases

  // staging: thread t covers row r0 (i=0) / r0+64 (i=1), pre-swizzled source chunk sc
  const int sc = (lane & 3) ^ ((lane >> 3) & 3);
  const int r0 = wave * 16 + (lane >> 2);
  const bf16* aSrc0 = A + (size_t)(bm * 128 + r0) * K + sc * 8;
  const bf16* aSrc1 = A + (size_t)(bm * 128 + 64 + r0) * K + sc * 8;
  const bf16* bSrc0 = Bt + (size_t)(bn * 128 + r0) * K + sc * 8;
  const bf16* bSrc1 = Bt + (size_t)(bn * 128 + 64 + r0) * K + sc * 8;
  bf16* aDst = As + wave * 512;  // wave-uniform base; HW adds lane*16B
  bf16* bDst = Bs + wave * 512;

  const int rw = (wave >> 1) * 64, cw = (wave & 1) * 64;  // 2M x 2N waves, 64x64 each
  // phys chunk for fragment reads: frag row base %16 -> (row>>1)&3 == (l15>>1)&3
  const int pc = (l4 ^ ((l15 >> 1) & 3)) * 8;

  f32x4 acc[4][4];
#pragma unroll
  for (int mi = 0; mi < 4; mi++)
#pragma unroll
    for (int ni = 0; ni < 4; ni++) { f32x4 z = {0.f, 0.f, 0.f, 0.f}; acc[mi][ni] = z; }

  // prologue: k-halves 0 and 1 into regions 0,1; wait G(0) (leave G(1) in flight)
  STG(0, 0);
  STG(1, 1);
  asm volatile("s_waitcnt vmcnt(4)" ::: "memory");
  BAR();
  __builtin_amdgcn_sched_barrier(0);

  int reg = 0, sreg = 2;
  for (int s = 0; s < ns; ++s) {
    const bf16* Ab = As + reg * 4096;
    const bf16* Bb = Bs + reg * 4096;
    if (s + 2 < ns) STG(s + 2, sreg);
    bf16x8 aF[4], bF[4];
#pragma unroll
    for (int mi = 0; mi < 4; mi++) aF[mi] = dsr16(Ab + (rw + mi * 16 + l15) * 32 + pc);
#pragma unroll
    for (int ni = 0; ni < 4; ni++) bF[ni] = dsr16(Bb + (cw + ni * 16 + l15) * 32 + pc);
    if (s + 2 < ns) asm volatile("s_waitcnt vmcnt(4)" ::: "memory");
    else            asm volatile("s_waitcnt vmcnt(0)" ::: "memory");
    asm volatile("s_waitcnt lgkmcnt(0)" ::: "memory");
    BAR();
    __builtin_amdgcn_sched_barrier(0);
    __builtin_amdgcn_s_setprio(1);
#pragma unroll
    for (int mi = 0; mi < 4; mi++)
#pragma unroll
      for (int ni = 0; ni < 4; ni++) acc[mi][ni] = mfma16(aF[mi], bF[ni], acc[mi][ni]);
    __builtin_amdgcn_s_setprio(0);
    reg = (reg == 2) ? 0 : reg + 1;
    sreg = (sreg == 2) ? 0 : sreg + 1;
  }

  // C/D layout (16x16, m89): col = lane&15, row = (lane>>4)*4 + e
#pragma unroll
  for (int mi = 0; mi < 4; mi++) {
#pragma unroll
    for (int ni = 0; ni < 4; ni++) {
      const int n = bn * 128 + cw + ni * 16 + l15;
#pragma unroll
      for (int e = 0; e < 4; e++) {
        const int m = bm * 128 + rw + mi * 16 + l4 * 4 + e;
        float val = acc[mi][ni][e];
        if constexpr (EPI == 0) {
          const int b = m >> 11, tt = m & 2047;
          if (n < D_MODEL) {
            const int hh = n >> 6, sgl = n & 63;
            q_out[(size_t)((b * N_HEAD + hh) * SEQ + tt) * HEAD + sgl] = (bf16)val;
          } else if (n < 2 * D_MODEL) {
            const int n2 = n - D_MODEL, hh = n2 >> 6, sgl = n2 & 63;
            k_out[(size_t)((b * N_HEAD + hh) * SEQ + tt) * HEAD + sgl] = (bf16)val;
          } else {
            const int n2 = n - 2 * D_MODEL, hh = n2 >> 6, sgl = n2 & 63;
            vt_out[(size_t)((b * N_HEAD + hh) * HEAD + sgl) * SEQ + tt] = (bf16)val;
          }
        } else if constexpr (EPI == 1) {
          ((float*)outp)[(size_t)m * N + n] = val + bias[n] + resid[(size_t)m * N + n];
        } else if constexpr (EPI == 2) {
          ((bf16*)outp)[(size_t)m * N + n] = (bf16)fast_gelu(val + bias[n]);
        } else {
          ((float*)outp)[(size_t)m * N + n] = val + bias[n] + resid[(size_t)m * N + n];
        }
      }
    }
  }
}

#undef STG

// plain (non-template) kernel wrappers: no template syntax at launch sites
__global__ __launch_bounds__(256, 3) void gemm_qkv_kernel(const bf16* __restrict__ A,
                                                          const bf16* __restrict__ Bt,
                                                          bf16* __restrict__ q_out,
                                                          bf16* __restrict__ k_out,
                                                          bf16* __restrict__ vt_out) {
  gemm_body<0>(A, Bt, D_MODEL, nullptr, nullptr, nullptr, q_out, k_out, vt_out, 3 * D_MODEL);
}

__global__ __launch_bounds__(256, 3) void gemm_proj_kernel(const bf16* __restrict__ A,
                                                           const bf16* __restrict__ Bt,
                                                           float* __restrict__ outp,
                                                           const float* __restrict__ bias,
                                                           const float* __restrict__ resid) {
  gemm_body<1>(A, Bt, D_MODEL, outp, bias, resid, nullptr, nullptr, nullptr, D_MODEL);
}

__global__ __launch_bounds__(256, 3) void gemm_ff1_kernel(const bf16* __restrict__ A,
                                                          const bf16* __restrict__ Bt,
                                                          bf16* __restrict__ outp,
                                                          const float* __restrict__ bias) {
  gemm_body<2>(A, Bt, D_MODEL, outp, bias, nullptr, nullptr, nullptr, nullptr, FFD);
}

__global__ __launch_bounds__(256, 3) void gemm_ff2_kernel(const bf16* __restrict__ A,
                                                          const bf16* __restrict__ Bt,
                                                          float* __restrict__ outp,
                                                          const float* __restrict__ bias,
                                                          const float* __restrict__ resid) {
  gemm_body<3>(A, Bt, FFD, outp, bias, resid, nullptr, nullptr, nullptr, D_MODEL);
}

// ---------------- attention: S^T trick + XOR-swizzled LDS staging (verified R3) ----------------
__global__ __launch_bounds__(256, 2) void attn_kernel(const bf16* __restrict__ q,
                                                      const bf16* __restrict__ k,
                                                      const bf16* __restrict__ vt,
                                                      bf16* __restrict__ att) {
  __shared__ bf16 Ks[64 * 64];
  __shared__ bf16 Vs[64 * 64];
  const int t = threadIdx.x, wave = t >> 6, lane = t & 63;
  const int l15 = lane & 15, l4 = lane >> 4;
  const int bh = blockIdx.x & 63, qblk = blockIdx.x >> 6;
  const bf16* qb = q + (size_t)bh * SEQ * HEAD;
  const bf16* kb = k + (size_t)bh * SEQ * HEAD;
  const bf16* vb = vt + (size_t)bh * HEAD * SEQ;
  const int qrow = qblk * 256 + wave * 64;

  const int tr = t >> 3, tc = t & 7, sw = tc ^ (tr & 7);
  const bf16* ksrc0 = kb + (size_t)tr * HEAD + sw * 8;
  const bf16* ksrc1 = kb + (size_t)(tr + 32) * HEAD + sw * 8;
  const bf16* vsrc0 = vb + (size_t)tr * SEQ + sw * 8;
  const bf16* vsrc1 = vb + (size_t)(tr + 32) * SEQ + sw * 8;
  bf16* kd0 = Ks + t * 8; bf16* kd1 = Ks + t * 8 + 2048;
  bf16* vd0 = Vs + t * 8; bf16* vd1 = Vs + t * 8 + 2048;

  const float qscale = 0.125f * 1.44269504088896340736f;
  bf16x8 qf[4][2];
#pragma unroll
  for (int qs = 0; qs < 4; qs++)
#pragma unroll
    for (int h = 0; h < 2; h++) {
      const bf16x8 raw = *(const bf16x8*)(qb + (size_t)(qrow + qs * 16 + l15) * HEAD + h * 32 + l4 * 8);
      bf16x8 sc;
#pragma unroll
      for (int e = 0; e < 8; e++) sc[e] = (bf16)((float)raw[e] * qscale);
      qf[qs][h] = sc;
    }

  f32x4 o[4][4];
  float lsum[4] = {0.f, 0.f, 0.f, 0.f};
#pragma unroll
  for (int qs = 0; qs < 4; qs++)
#pragma unroll
    for (int dm = 0; dm < 4; dm++) { f32x4 z = {0.f, 0.f, 0.f, 0.f}; o[qs][dm] = z; }

  const int rsw = l15 & 7;

  for (int u0 = 0; u0 < SEQ; u0 += 64) {
    __syncthreads();
    async_copy16(ksrc0 + (size_t)u0 * HEAD, kd0);
    async_copy16(ksrc1 + (size_t)u0 * HEAD, kd1);
    async_copy16(vsrc0 + u0, vd0);
    async_copy16(vsrc1 + u0, vd1);
    __syncthreads();

    bf16x8 kf[4][2];
#pragma unroll
    for (int n = 0; n < 4; n++)
#pragma unroll
      for (int h = 0; h < 2; h++)
        kf[n][h] = *(const bf16x8*)(Ks + (n * 16 + l15) * 64 + (((h << 2) | l4) ^ rsw) * 8);
    bf16x4 vf[4][4];
#pragma unroll
    for (int dm = 0; dm < 4; dm++)
#pragma unroll
      for (int n = 0; n < 4; n++)
        vf[dm][n] = *(const bf16x4*)(Vs + (dm * 16 + l15) * 64 + ((((n << 1) | (l4 >> 1)) ^ rsw) * 8) + (l4 & 1) * 4);

#pragma unroll
    for (int qs = 0; qs < 4; qs++) {
      f32x4 s[4];
#pragma unroll
      for (int n = 0; n < 4; n++) {
        f32x4 c = {0.f, 0.f, 0.f, 0.f};
        c = mfma16(kf[n][0], qf[qs][0], c);
        c = mfma16(kf[n][1], qf[qs][1], c);
        s[n] = c;
      }
      if (u0 == qrow) {
#pragma unroll
        for (int r = 0; r < 4; r++)
          s[qs][r] = (l15 == l4 * 4 + r) ? 0.f : s[qs][r];
      }
      bf16x4 pf[4];
      float ls = 0.f;
#pragma unroll
      for (int n = 0; n < 4; n++) {
        f32x4 pv;
#pragma unroll
        for (int r = 0; r < 4; r++) { pv[r] = fast_exp2(s[n][r]); ls += pv[r]; }
        bf16x4 pb;
#pragma unroll
        for (int r = 0; r < 4; r++) pb[r] = (bf16)pv[r];
        pf[n] = pb;
      }
      lsum[qs] += ls;
#pragma unroll
      for (int dm = 0; dm < 4; dm++) {
        f32x4 acc = o[qs][dm];
#pragma unroll
        for (int n = 0; n < 4; n++) acc = mfma16k16(vf[dm][n], pf[n], acc);
        o[qs][dm] = acc;
      }
    }
  }

#pragma unroll
  for (int qs = 0; qs < 4; qs++) {
    float l = lsum[qs];
    l += __shfl_xor(l, 16);
    l += __shfl_xor(l, 32);
    lsum[qs] = l;
  }
  const int b = bh >> 4, hh = bh & 15;
#pragma unroll
  for (int qs = 0; qs < 4; qs++) {
    const float linv = 1.0f / lsum[qs];
#pragma unroll
    for (int dm = 0; dm < 4; dm++) {
      bf16x4 ov;
#pragma unroll
      for (int r = 0; r < 4; r++) ov[r] = (bf16)(o[qs][dm][r] * linv);
      *(bf16x4*)(att + (size_t)(b * SEQ + qrow + qs * 16 + l15) * D_MODEL + hh * HEAD + dm * 16 + l4 * 4) = ov;
    }
  }
}

extern "C" void kernel_launch(void* const* d_in, const int* in_sizes, int n_in,
                              void* d_out, int out_size, void* d_ws, size_t ws_size,
                              hipStream_t stream) {
  const float* x   = (const float*)d_in[0];
  const float* Wq  = (const float*)d_in[1];
  const float* Wk  = (const float*)d_in[2];
  const float* Wv  = (const float*)d_in[3];
  const float* Wo  = (const float*)d_in[4];
  const float* bo  = (const float*)d_in[5];
  const float* W1  = (const float*)d_in[6];
  const float* b1  = (const float*)d_in[7];
  const float* W2  = (const float*)d_in[8];
  const float* b2  = (const float*)d_in[9];
  const float* g1  = (const float*)d_in[10];
  const float* be1 = (const float*)d_in[11];
  const float* g2  = (const float*)d_in[12];
  const float* be2 = (const float*)d_in[13];
  float* out = (float*)d_out;

  bf16* Wqkv_t = (bf16*)d_ws;                                  // [3][1024][1024]
  bf16* Wo_t   = Wqkv_t + (size_t)3 * D_MODEL * D_MODEL;       // [1024][1024]
  bf16* W1_t   = Wo_t + (size_t)D_MODEL * D_MODEL;             // [4096][1024]
  bf16* W2_t   = W1_t + (size_t)FFD * D_MODEL;                 // [1024][4096]
  bf16* hbuf   = W2_t + (size_t)D_MODEL * FFD;                 // [8192][1024] (h, later h2)
  float* x1    = (float*)(hbuf + (size_t)ROWS * D_MODEL);      // [8192][1024] fp32
  bf16* big    = (bf16*)(x1 + (size_t)ROWS * D_MODEL);         // qkv (50MB) then ff (64MB)
  bf16* qbuf   = big;
  bf16* kbuf   = qbuf + (size_t)ROWS * D_MODEL;
  bf16* vtbuf  = kbuf + (size_t)ROWS * D_MODEL;
  bf16* ffbuf  = big;                                          // reuse after attention
  bf16* attb   = big + (size_t)ROWS * FFD;                     // [8192][1024]

  qkv_transpose_kernel<<<dim3(D_MODEL / 32, HEAD / 32, 3 * N_HEAD), 256, 0, stream>>>(Wq, Wk, Wv, Wqkv_t);
  transpose_cast_kernel<<<dim3(D_MODEL / 32, D_MODEL / 32), 256, 0, stream>>>(Wo, Wo_t, D_MODEL, D_MODEL);
  transpose_cast_kernel<<<dim3(FFD / 32, D_MODEL / 32), 256, 0, stream>>>(W1, W1_t, D_MODEL, FFD);
  transpose_cast_kernel<<<dim3(D_MODEL / 32, FFD / 32), 256, 0, stream>>>(W2, W2_t, FFD, D_MODEL);
  ln_kernel<<<ROWS, 256, 0, stream>>>(x, g1, be1, hbuf);
  // grids: (N/128)*(M/128) blocks, 1D, all %8==0 for the XCD swizzle; 3 blocks/CU resident
  gemm_qkv_kernel<<<dim3((3 * D_MODEL / 128) * (ROWS / 128)), 256, 0, stream>>>(
      hbuf, Wqkv_t, qbuf, kbuf, vtbuf);
  attn_kernel<<<64 * (SEQ / 256), 256, 0, stream>>>(qbuf, kbuf, vtbuf, attb);
  gemm_proj_kernel<<<dim3((D_MODEL / 128) * (ROWS / 128)), 256, 0, stream>>>(
      attb, Wo_t, x1, bo, x);
  ln_kernel<<<ROWS, 256, 0, stream>>>(x1, g2, be2, hbuf);
  gemm_ff1_kernel<<<dim3((FFD / 128) * (ROWS / 128)), 256, 0, stream>>>(
      hbuf, W1_t, ffbuf, b1);
  gemm_ff2_kernel<<<dim3((D_MODEL / 128) * (ROWS / 128)), 256, 0, stream>>>(
      ffbuf, W2_t, out, b2, x1);
}

// Round 6
// 524.478 us; speedup vs baseline: 1.0924x; 1.0676x over previous
//
#include <hip/hip_runtime.h>
#include <hip/hip_bf16.h>
#include <math.h>

#define D_MODEL 1024
#define N_HEAD 16
#define HEAD 64
#define SEQ 2048
#define BATCH 4
#define ROWS (BATCH*SEQ)
#define FFD 4096

typedef __bf16 bf16;
typedef __attribute__((ext_vector_type(8))) __bf16 bf16x8;
typedef __attribute__((ext_vector_type(4))) __bf16 bf16x4;
typedef __attribute__((ext_vector_type(4))) float f32x4;
typedef __attribute__((ext_vector_type(4))) short short4v;

static_assert(sizeof(bf16x8) == 16, "bf16x8 must be 16B");

__device__ __forceinline__ void async_copy16(const void* g, void* l) {
  __builtin_amdgcn_global_load_lds((const __attribute__((address_space(1))) void*)g,
                                   (__attribute__((address_space(3))) void*)l, 16, 0, 0);
}

// Opaque LDS read: invisible to the waitcnt legalizer; ordering = our asm waits +
// sched_barrier(0) before consumers (rule #18).
__device__ __forceinline__ bf16x8 dsr16(const bf16* p) {
  bf16x8 r;
  const __attribute__((address_space(3))) bf16* lp =
      (const __attribute__((address_space(3))) bf16*)(unsigned int)(size_t)p;
  asm volatile("ds_read_b128 %0, %1" : "=v"(r) : "v"(lp));
  return r;
}

#define BAR() asm volatile("s_barrier" ::: "memory")
#define LGKM0() do { asm volatile("s_waitcnt lgkmcnt(0)" ::: "memory"); \
                     __builtin_amdgcn_sched_barrier(0); } while (0)

__device__ __forceinline__ f32x4 mfma16(bf16x8 a, bf16x8 b, f32x4 c) {
  return __builtin_amdgcn_mfma_f32_16x16x32_bf16(a, b, c, 0, 0, 0);
}

__device__ __forceinline__ f32x4 mfma16k16(bf16x4 a, bf16x4 b, f32x4 c) {
#if __has_builtin(__builtin_amdgcn_mfma_f32_16x16x16_bf16)
  return __builtin_amdgcn_mfma_f32_16x16x16_bf16(a, b, c, 0, 0, 0);
#else
  return __builtin_amdgcn_mfma_f32_16x16x16bf16_1k(__builtin_bit_cast(short4v, a),
                                                   __builtin_bit_cast(short4v, b), c, 0, 0, 0);
#endif
}

__device__ __forceinline__ float fast_exp2(float x) {
#if __has_builtin(__builtin_amdgcn_exp2f)
  return __builtin_amdgcn_exp2f(x);
#else
  float r; asm("v_exp_f32 %0, %1" : "=v"(r) : "v"(x)); return r;
#endif
}

// tanh-form GELU: max abs dev vs exact erf-GELU ~1e-3 pre-W2; well inside threshold.
__device__ __forceinline__ float fast_gelu(float x) {
  const float y = 0.7978845608f * (x + 0.044715f * x * x * x);
  const float e = fast_exp2(y * 2.88539008178f);  // exp(2y)
  return 0.5f * x * (1.f + (1.f - 2.f / (e + 1.f)));
}

// ---------------- weight transpose + cast: in fp32 [R][C] -> out bf16 [C][R] ----------------
__global__ __launch_bounds__(256) void transpose_cast_kernel(const float* __restrict__ in,
                                                             bf16* __restrict__ out,
                                                             int R, int C) {
  __shared__ float ts[32][33];
  const int r0 = blockIdx.y * 32, c0 = blockIdx.x * 32;
  const int t = threadIdx.x, lr = t >> 3, lc = (t & 7) * 4;
  const float4 v = *(const float4*)(in + (size_t)(r0 + lr) * C + c0 + lc);
  ts[lr][lc + 0] = v.x; ts[lr][lc + 1] = v.y; ts[lr][lc + 2] = v.z; ts[lr][lc + 3] = v.w;
  __syncthreads();
  bf16x4 o;
  o[0] = (bf16)ts[lc + 0][lr]; o[1] = (bf16)ts[lc + 1][lr];
  o[2] = (bf16)ts[lc + 2][lr]; o[3] = (bf16)ts[lc + 3][lr];
  *(bf16x4*)(out + (size_t)(c0 + lr) * R + r0 + lc) = o;
}

// Wq/Wk/Wv [H][C][hs] fp32 -> out bf16 [3][N=H*hs][K=C]  (B^T layout for the QKV GEMM)
__global__ __launch_bounds__(256) void qkv_transpose_kernel(const float* __restrict__ Wq,
                                                            const float* __restrict__ Wk,
                                                            const float* __restrict__ Wv,
                                                            bf16* __restrict__ out) {
  __shared__ float ts[32][33];
  const int mat = blockIdx.z / N_HEAD, h = blockIdx.z % N_HEAD;
  const float* W = (mat == 0 ? Wq : mat == 1 ? Wk : Wv) + (size_t)h * D_MODEL * HEAD;
  bf16* o = out + (size_t)mat * D_MODEL * D_MODEL + (size_t)(h * HEAD) * D_MODEL;
  const int c0 = blockIdx.x * 32, s0 = blockIdx.y * 32;
  const int t = threadIdx.x, lr = t >> 3, lc = (t & 7) * 4;
  const float4 v = *(const float4*)(W + (size_t)(c0 + lr) * HEAD + s0 + lc);
  ts[lr][lc + 0] = v.x; ts[lr][lc + 1] = v.y; ts[lr][lc + 2] = v.z; ts[lr][lc + 3] = v.w;
  __syncthreads();
  bf16x4 ov;
  ov[0] = (bf16)ts[lc + 0][lr]; ov[1] = (bf16)ts[lc + 1][lr];
  ov[2] = (bf16)ts[lc + 2][lr]; ov[3] = (bf16)ts[lc + 3][lr];
  *(bf16x4*)(o + (size_t)(s0 + lr) * D_MODEL + c0 + lc) = ov;
}

// ---------------- LayerNorm: fp32 in -> bf16 out, one block per row ----------------
__global__ __launch_bounds__(256) void ln_kernel(const float* __restrict__ x,
                                                 const float* __restrict__ g,
                                                 const float* __restrict__ b,
                                                 bf16* __restrict__ h) {
  const int row = blockIdx.x, t = threadIdx.x;
  const float4 v = *(const float4*)(x + (size_t)row * D_MODEL + t * 4);
  float s = v.x + v.y + v.z + v.w;
  float ss = v.x * v.x + v.y * v.y + v.z * v.z + v.w * v.w;
#pragma unroll
  for (int m = 1; m < 64; m <<= 1) { s += __shfl_xor(s, m); ss += __shfl_xor(ss, m); }
  __shared__ float red[8];
  const int wave = t >> 6, lane = t & 63;
  if (lane == 0) { red[wave] = s; red[4 + wave] = ss; }
  __syncthreads();
  s = red[0] + red[1] + red[2] + red[3];
  ss = red[4] + red[5] + red[6] + red[7];
  const float mu = s * (1.f / D_MODEL);
  const float rstd = rsqrtf(ss * (1.f / D_MODEL) - mu * mu + 1e-5f);
  const float4 gv = *(const float4*)(g + t * 4);
  const float4 bv = *(const float4*)(b + t * 4);
  bf16x4 o;
  o[0] = (bf16)((v.x - mu) * rstd * gv.x + bv.x);
  o[1] = (bf16)((v.y - mu) * rstd * gv.y + bv.y);
  o[2] = (bf16)((v.z - mu) * rstd * gv.z + bv.z);
  o[3] = (bf16)((v.w - mu) * rstd * gv.w + bv.w);
  *(bf16x4*)(h + (size_t)row * D_MODEL + t * 4) = o;
}

// ---------------- m201-template GEMM: BMx256 tile, 8 waves, phase = (k-half, m-half) ----------
// C[M][N] = A[M][K] x Bt[N][K], bf16 rm. BN=256 always, BK=64 = 2 k-half regions [kk][rows][32].
// dbuf: buf[kt&1]; stages during kt target buf[(kt+1)&1] (dead since kt-1) -> no clobber ever.
// Phase (template-faithful): { ds_reads issued; stage 1 half-region; BAR; lgkm(0)+SB0;
//   setprio1; 16 MFMA; setprio0; [counted vmcnt]; BAR }  — reads in flight ACROSS the first
// barrier (latency overlaps barrier skew; the R2-R5 mistake was lgkm(0) before the barrier).
// BM=256 (4 phases/tile: (kk0,mh0),(kk0,mh1),(kk1,mh0),(kk1,mh1); stages A'k0,B'k0,A'k1,B'k1):
//   vmcnt(4) at end of P2 and P4. Counter simulation (steady): after P4-wait 4 outstanding
//   = {A'k1,B'k1}; P1,P2 add 4 -> 8; P2-wait drains to 4 = exactly the halves needed at P3;
//   P4-wait drains P1,P2's stages = halves needed at next-tile P1. Slack 3-4 phases > HBM lat.
// BM=128 (2 phases/tile: kk0,kk1; stages {A'kk,B'kk} per phase): vmcnt(3) per phase, slack 2.
// Swizzle (verified 0-conflict R2-R5): global-source chunk sc=(lane&3)^((lane>>3)&3), read
// chunk pc=(l4^((l15>>1)&3))*8, lane-linear gload_lds dests (rule #21).
template <int EPI>
__device__ __forceinline__ void gemm_epi(int m, int n, float val, void* outp,
                                         const float* bias, const float* resid,
                                         bf16* q_out, bf16* k_out, bf16* vt_out, int N) {
  if constexpr (EPI == 0) {
    const int b = m >> 11, tt = m & 2047;
    if (n < D_MODEL) {
      const int hh = n >> 6, sgl = n & 63;
      q_out[(size_t)((b * N_HEAD + hh) * SEQ + tt) * HEAD + sgl] = (bf16)val;
    } else if (n < 2 * D_MODEL) {
      const int n2 = n - D_MODEL, hh = n2 >> 6, sgl = n2 & 63;
      k_out[(size_t)((b * N_HEAD + hh) * SEQ + tt) * HEAD + sgl] = (bf16)val;
    } else {
      const int n2 = n - 2 * D_MODEL, hh = n2 >> 6, sgl = n2 & 63;
      vt_out[(size_t)((b * N_HEAD + hh) * HEAD + sgl) * SEQ + tt] = (bf16)val;
    }
  } else if constexpr (EPI == 1) {
    ((float*)outp)[(size_t)m * N + n] = val + bias[n] + resid[(size_t)m * N + n];
  } else if constexpr (EPI == 2) {
    ((bf16*)outp)[(size_t)m * N + n] = (bf16)fast_gelu(val + bias[n]);
  } else {
    ((float*)outp)[(size_t)m * N + n] = val + bias[n] + resid[(size_t)m * N + n];
  }
}

template <int EPI>
__device__ __forceinline__ void gemm_body256(const bf16* A, const bf16* Bt, int K,
                                             void* outp, const float* bias,
                                             const float* resid, bf16* q_out,
                                             bf16* k_out, bf16* vt_out, int N) {
  __shared__ __align__(16) bf16 As[2 * 2 * 8192];   // [buf][kk][256][32] 64 KB
  __shared__ __align__(16) bf16 Bs[2 * 2 * 8192];   // 64 KB
  const int t = threadIdx.x, wave = t >> 6, lane = t & 63;
  const int l15 = lane & 15, l4 = lane >> 4;
  const int lin = ((int)blockIdx.x & 7) * ((int)gridDim.x >> 3) + ((int)blockIdx.x >> 3);
  const int nbn = N >> 8;
  const int bn = lin % nbn, bm = lin / nbn;
  const int nk = K >> 6;

  const int sc = (lane & 3) ^ ((lane >> 3) & 3);
  const int r0 = wave * 16 + (lane >> 2);
  const bf16* aSrc0 = A + (size_t)(bm * 256 + r0) * K + sc * 8;
  const bf16* aSrc1 = A + (size_t)(bm * 256 + 128 + r0) * K + sc * 8;
  const bf16* bSrc0 = Bt + (size_t)(bn * 256 + r0) * K + sc * 8;
  const bf16* bSrc1 = Bt + (size_t)(bn * 256 + 128 + r0) * K + sc * 8;

  const int wm = wave >> 2, wn = wave & 3;
  const int rw = wm * 128, cw = wn * 64;
  const int pc = (l4 ^ ((l15 >> 1) & 3)) * 8;

#define STG_A(kt2, kk)                                                              \
  do { const int o_ = (kt2) * 64 + (kk) * 32;                                       \
       bf16* d_ = As + (((kt2) & 1) * 2 + (kk)) * 8192 + wave * 512;                \
       async_copy16(aSrc0 + o_, d_); async_copy16(aSrc1 + o_, d_ + 4096); } while (0)
#define STG_B(kt2, kk)                                                              \
  do { const int o_ = (kt2) * 64 + (kk) * 32;                                       \
       bf16* d_ = Bs + (((kt2) & 1) * 2 + (kk)) * 8192 + wave * 512;                \
       async_copy16(bSrc0 + o_, d_); async_copy16(bSrc1 + o_, d_ + 4096); } while (0)

  f32x4 acc[8][4];
#pragma unroll
  for (int mi = 0; mi < 8; mi++)
#pragma unroll
    for (int ni = 0; ni < 4; ni++) { f32x4 z = {0.f, 0.f, 0.f, 0.f}; acc[mi][ni] = z; }

  // prologue: tile 0's four half-regions; vmcnt(4) -> kk0 halves resident, kk1 in flight
  STG_A(0, 0); STG_B(0, 0); STG_A(0, 1); STG_B(0, 1);
  asm volatile("s_waitcnt vmcnt(4)" ::: "memory");
  BAR();
  __builtin_amdgcn_sched_barrier(0);

  for (int kt = 0; kt < nk; kt++) {
    const bf16* Ab = As + (kt & 1) * 16384;
    const bf16* Bb = Bs + (kt & 1) * 16384;
    const bool pf = (kt + 1 < nk);
    bf16x8 aF[4], bF[4];

    // ---- P1 (kk0, mh0): 8 reads, stage A'(kk0)
#pragma unroll
    for (int mi = 0; mi < 4; mi++) aF[mi] = dsr16(Ab + (rw + mi * 16 + l15) * 32 + pc);
#pragma unroll
    for (int ni = 0; ni < 4; ni++) bF[ni] = dsr16(Bb + (cw + ni * 16 + l15) * 32 + pc);
    if (pf) STG_A(kt + 1, 0);
    BAR();
    LGKM0();
    __builtin_amdgcn_s_setprio(1);
#pragma unroll
    for (int mi = 0; mi < 4; mi++)
#pragma unroll
      for (int ni = 0; ni < 4; ni++) acc[mi][ni] = mfma16(aF[mi], bF[ni], acc[mi][ni]);
    __builtin_amdgcn_s_setprio(0);
    BAR();

    // ---- P2 (kk0, mh1): 4 reads (B reused), stage B'(kk0), vmcnt(4)
#pragma unroll
    for (int mi = 0; mi < 4; mi++) aF[mi] = dsr16(Ab + (rw + (4 + mi) * 16 + l15) * 32 + pc);
    if (pf) STG_B(kt + 1, 0);
    BAR();
    LGKM0();
    __builtin_amdgcn_s_setprio(1);
#pragma unroll
    for (int mi = 0; mi < 4; mi++)
#pragma unroll
      for (int ni = 0; ni < 4; ni++) acc[4 + mi][ni] = mfma16(aF[mi], bF[ni], acc[4 + mi][ni]);
    __builtin_amdgcn_s_setprio(0);
    if (pf) asm volatile("s_waitcnt vmcnt(4)" ::: "memory");
    else    asm volatile("s_waitcnt vmcnt(0)" ::: "memory");
    BAR();

    // ---- P3 (kk1, mh0): 8 reads, stage A'(kk1)
#pragma unroll
    for (int mi = 0; mi < 4; mi++) aF[mi] = dsr16(Ab + 8192 + (rw + mi * 16 + l15) * 32 + pc);
#pragma unroll
    for (int ni = 0; ni < 4; ni++) bF[ni] = dsr16(Bb + 8192 + (cw + ni * 16 + l15) * 32 + pc);
    if (pf) STG_A(kt + 1, 1);
    BAR();
    LGKM0();
    __builtin_amdgcn_s_setprio(1);
#pragma unroll
    for (int mi = 0; mi < 4; mi++)
#pragma unroll
      for (int ni = 0; ni < 4; ni++) acc[mi][ni] = mfma16(aF[mi], bF[ni], acc[mi][ni]);
    __builtin_amdgcn_s_setprio(0);
    BAR();

    // ---- P4 (kk1, mh1): 4 reads, stage B'(kk1), vmcnt(4)
#pragma unroll
    for (int mi = 0; mi < 4; mi++) aF[mi] = dsr16(Ab + 8192 + (rw + (4 + mi) * 16 + l15) * 32 + pc);
    if (pf) STG_B(kt + 1, 1);
    BAR();
    LGKM0();
    __builtin_amdgcn_s_setprio(1);
#pragma unroll
    for (int mi = 0; mi < 4; mi++)
#pragma unroll
      for (int ni = 0; ni < 4; ni++) acc[4 + mi][ni] = mfma16(aF[mi], bF[ni], acc[4 + mi][ni]);
    __builtin_amdgcn_s_setprio(0);
    if (pf) asm volatile("s_waitcnt vmcnt(4)" ::: "memory");
    else    asm volatile("s_waitcnt vmcnt(0)" ::: "memory");
    BAR();
  }
#undef STG_A
#undef STG_B

#pragma unroll
  for (int mi = 0; mi < 8; mi++)
#pragma unroll
    for (int ni = 0; ni < 4; ni++) {
      const int n = bn * 256 + cw + ni * 16 + l15;
#pragma unroll
      for (int e = 0; e < 4; e++) {
        const int m = bm * 256 + rw + mi * 16 + l4 * 4 + e;
        gemm_epi<EPI>(m, n, acc[mi][ni][e], outp, bias, resid, q_out, k_out, vt_out, N);
      }
    }
}

template <int EPI>
__device__ __forceinline__ void gemm_body128(const bf16* A, const bf16* Bt, int K,
                                             void* outp, const float* bias,
                                             const float* resid, bf16* q_out,
                                             bf16* k_out, bf16* vt_out, int N) {
  __shared__ __align__(16) bf16 As[2 * 2 * 4096];   // [buf][kk][128][32] 32 KB
  __shared__ __align__(16) bf16 Bs[2 * 2 * 8192];   // [buf][kk][256][32] 64 KB
  const int t = threadIdx.x, wave = t >> 6, lane = t & 63;
  const int l15 = lane & 15, l4 = lane >> 4;
  const int lin = ((int)blockIdx.x & 7) * ((int)gridDim.x >> 3) + ((int)blockIdx.x >> 3);
  const int nbn = N >> 8;
  const int bn = lin % nbn, bm = lin / nbn;
  const int nk = K >> 6;

  const int sc = (lane & 3) ^ ((lane >> 3) & 3);
  const int r0 = wave * 16 + (lane >> 2);
  const bf16* aSrc0 = A + (size_t)(bm * 128 + r0) * K + sc * 8;
  const bf16* bSrc0 = Bt + (size_t)(bn * 256 + r0) * K + sc * 8;
  const bf16* bSrc1 = Bt + (size_t)(bn * 256 + 128 + r0) * K + sc * 8;

  const int wm = wave >> 2, wn = wave & 3;
  const int rw = wm * 64, cw = wn * 64;
  const int pc = (l4 ^ ((l15 >> 1) & 3)) * 8;

#define STG(kt2, kk)                                                                \
  do { const int o_ = (kt2) * 64 + (kk) * 32;                                       \
       bf16* ad_ = As + (((kt2) & 1) * 2 + (kk)) * 4096 + wave * 512;               \
       bf16* bd_ = Bs + (((kt2) & 1) * 2 + (kk)) * 8192 + wave * 512;               \
       async_copy16(aSrc0 + o_, ad_);                                               \
       async_copy16(bSrc0 + o_, bd_); async_copy16(bSrc1 + o_, bd_ + 4096); } while (0)

  f32x4 acc[4][4];
#pragma unroll
  for (int mi = 0; mi < 4; mi++)
#pragma unroll
    for (int ni = 0; ni < 4; ni++) { f32x4 z = {0.f, 0.f, 0.f, 0.f}; acc[mi][ni] = z; }

  STG(0, 0); STG(0, 1);
  asm volatile("s_waitcnt vmcnt(3)" ::: "memory");
  BAR();
  __builtin_amdgcn_sched_barrier(0);

  for (int kt = 0; kt < nk; kt++) {
    const bool pf = (kt + 1 < nk);
    bf16x8 aF[4], bF[4];
#pragma unroll
    for (int kk = 0; kk < 2; kk++) {
      const bf16* Ab = As + ((kt & 1) * 2 + kk) * 4096;
      const bf16* Bb = Bs + ((kt & 1) * 2 + kk) * 8192;
#pragma unroll
      for (int mi = 0; mi < 4; mi++) aF[mi] = dsr16(Ab + (rw + mi * 16 + l15) * 32 + pc);
#pragma unroll
      for (int ni = 0; ni < 4; ni++) bF[ni] = dsr16(Bb + (cw + ni * 16 + l15) * 32 + pc);
      if (pf) STG(kt + 1, kk);
      BAR();
      LGKM0();
      __builtin_amdgcn_s_setprio(1);
#pragma unroll
      for (int mi = 0; mi < 4; mi++)
#pragma unroll
        for (int ni = 0; ni < 4; ni++) acc[mi][ni] = mfma16(aF[mi], bF[ni], acc[mi][ni]);
      __builtin_amdgcn_s_setprio(0);
      if (pf) asm volatile("s_waitcnt vmcnt(3)" ::: "memory");
      else    asm volatile("s_waitcnt vmcnt(0)" ::: "memory");
      BAR();
    }
  }
#undef STG

#pragma unroll
  for (int mi = 0; mi < 4; mi++)
#pragma unroll
    for (int ni = 0; ni < 4; ni++) {
      const int n = bn * 256 + cw + ni * 16 + l15;
#pragma unroll
      for (int e = 0; e < 4; e++) {
        const int m = bm * 128 + rw + mi * 16 + l4 * 4 + e;
        gemm_epi<EPI>(m, n, acc[mi][ni][e], outp, bias, resid, q_out, k_out, vt_out, N);
      }
    }
}

// plain wrappers (no template syntax at launch sites)
__global__ __launch_bounds__(512, 2) void gemm_qkv_kernel(const bf16* __restrict__ A,
                                                          const bf16* __restrict__ Bt,
                                                          bf16* __restrict__ q_out,
                                                          bf16* __restrict__ k_out,
                                                          bf16* __restrict__ vt_out) {
  gemm_body128<0>(A, Bt, D_MODEL, nullptr, nullptr, nullptr, q_out, k_out, vt_out, 3 * D_MODEL);
}

__global__ __launch_bounds__(512, 2) void gemm_proj_kernel(const bf16* __restrict__ A,
                                                           const bf16* __restrict__ Bt,
                                                           float* __restrict__ outp,
                                                           const float* __restrict__ bias,
                                                           const float* __restrict__ resid) {
  gemm_body128<1>(A, Bt, D_MODEL, outp, bias, resid, nullptr, nullptr, nullptr, D_MODEL);
}

__global__ __launch_bounds__(512, 2) void gemm_ff1_kernel(const bf16* __restrict__ A,
                                                          const bf16* __restrict__ Bt,
                                                          bf16* __restrict__ outp,
                                                          const float* __restrict__ bias) {
  gemm_body256<2>(A, Bt, D_MODEL, outp, bias, nullptr, nullptr, nullptr, nullptr, FFD);
}

__global__ __launch_bounds__(512, 2) void gemm_ff2_kernel(const bf16* __restrict__ A,
                                                          const bf16* __restrict__ Bt,
                                                          float* __restrict__ outp,
                                                          const float* __restrict__ bias,
                                                          const float* __restrict__ resid) {
  gemm_body128<3>(A, Bt, FFD, outp, bias, resid, nullptr, nullptr, nullptr, D_MODEL);
}

// ---------------- attention: S^T trick + XOR-swizzled LDS staging (verified) ----------------
__global__ __launch_bounds__(256, 2) void attn_kernel(const bf16* __restrict__ q,
                                                      const bf16* __restrict__ k,
                                                      const bf16* __restrict__ vt,
                                                      bf16* __restrict__ att) {
  __shared__ bf16 Ks[64 * 64];
  __shared__ bf16 Vs[64 * 64];
  const int t = threadIdx.x, wave = t >> 6, lane = t & 63;
  const int l15 = lane & 15, l4 = lane >> 4;
  const int bh = blockIdx.x & 63, qblk = blockIdx.x >> 6;
  const bf16* qb = q + (size_t)bh * SEQ * HEAD;
  const bf16* kb = k + (size_t)bh * SEQ * HEAD;
  const bf16* vb = vt + (size_t)bh * HEAD * SEQ;
  const int qrow = qblk * 256 + wave * 64;

  const int tr = t >> 3, tc = t & 7, sw = tc ^ (tr & 7);
  const bf16* ksrc0 = kb + (size_t)tr * HEAD + sw * 8;
  const bf16* ksrc1 = kb + (size_t)(tr + 32) * HEAD + sw * 8;
  const bf16* vsrc0 = vb + (size_t)tr * SEQ + sw * 8;
  const bf16* vsrc1 = vb + (size_t)(tr + 32) * SEQ + sw * 8;
  bf16* kd0 = Ks + t * 8; bf16* kd1 = Ks + t * 8 + 2048;
  bf16* vd0 = Vs + t * 8; bf16* vd1 = Vs + t * 8 + 2048;

  const float qscale = 0.125f * 1.44269504088896340736f;
  bf16x8 qf[4][2];
#pragma unroll
  for (int qs = 0; qs < 4; qs++)
#pragma unroll
    for (int h = 0; h < 2; h++) {
      const bf16x8 raw = *(const bf16x8*)(qb + (size_t)(qrow + qs * 16 + l15) * HEAD + h * 32 + l4 * 8);
      bf16x8 sc;
#pragma unroll
      for (int e = 0; e < 8; e++) sc[e] = (bf16)((float)raw[e] * qscale);
      qf[qs][h] = sc;
    }

  f32x4 o[4][4];
  float lsum[4] = {0.f, 0.f, 0.f, 0.f};
#pragma unroll
  for (int qs = 0; qs < 4; qs++)
#pragma unroll
    for (int dm = 0; dm < 4; dm++) { f32x4 z = {0.f, 0.f, 0.f, 0.f}; o[qs][dm] = z; }

  const int rsw = l15 & 7;

  for (int u0 = 0; u0 < SEQ; u0 += 64) {
    __syncthreads();
    async_copy16(ksrc0 + (size_t)u0 * HEAD, kd0);
    async_copy16(ksrc1 + (size_t)u0 * HEAD, kd1);
    async_copy16(vsrc0 + u0, vd0);
    async_copy16(vsrc1 + u0, vd1);
    __syncthreads();

    bf16x8 kf[4][2];
#pragma unroll
    for (int n = 0; n < 4; n++)
#pragma unroll
      for (int h = 0; h < 2; h++)
        kf[n][h] = *(const bf16x8*)(Ks + (n * 16 + l15) * 64 + (((h << 2) | l4) ^ rsw) * 8);
    bf16x4 vf[4][4];
#pragma unroll
    for (int dm = 0; dm < 4; dm++)
#pragma unroll
      for (int n = 0; n < 4; n++)
        vf[dm][n] = *(const bf16x4*)(Vs + (dm * 16 + l15) * 64 + ((((n << 1) | (l4 >> 1)) ^ rsw) * 8) + (l4 & 1) * 4);

#pragma unroll
    for (int qs = 0; qs < 4; qs++) {
      f32x4 s[4];
#pragma unroll
      for (int n = 0; n < 4; n++) {
        f32x4 c = {0.f, 0.f, 0.f, 0.f};
        c = mfma16(kf[n][0], qf[qs][0], c);
        c = mfma16(kf[n][1], qf[qs][1], c);
        s[n] = c;
      }
      if (u0 == qrow) {
#pragma unroll
        for (int r = 0; r < 4; r++)
          s[qs][r] = (l15 == l4 * 4 + r) ? 0.f : s[qs][r];
      }
      bf16x4 pf[4];
      float ls = 0.f;
#pragma unroll
      for (int n = 0; n < 4; n++) {
        f32x4 pv;
#pragma unroll
        for (int r = 0; r < 4; r++) { pv[r] = fast_exp2(s[n][r]); ls += pv[r]; }
        bf16x4 pb;
#pragma unroll
        for (int r = 0; r < 4; r++) pb[r] = (bf16)pv[r];
        pf[n] = pb;
      }
      lsum[qs] += ls;
#pragma unroll
      for (int dm = 0; dm < 4; dm++) {
        f32x4 acc = o[qs][dm];
#pragma unroll
        for (int n = 0; n < 4; n++) acc = mfma16k16(vf[dm][n], pf[n], acc);
        o[qs][dm] = acc;
      }
    }
  }

#pragma unroll
  for (int qs = 0; qs < 4; qs++) {
    float l = lsum[qs];
    l += __shfl_xor(l, 16);
    l += __shfl_xor(l, 32);
    lsum[qs] = l;
  }
  const int b = bh >> 4, hh = bh & 15;
#pragma unroll
  for (int qs = 0; qs < 4; qs++) {
    const float linv = 1.0f / lsum[qs];
#pragma unroll
    for (int dm = 0; dm < 4; dm++) {
      bf16x4 ov;
#pragma unroll
      for (int r = 0; r < 4; r++) ov[r] = (bf16)(o[qs][dm][r] * linv);
      *(bf16x4*)(att + (size_t)(b * SEQ + qrow + qs * 16 + l15) * D_MODEL + hh * HEAD + dm * 16 + l4 * 4) = ov;
    }
  }
}

extern "C" void kernel_launch(void* const* d_in, const int* in_sizes, int n_in,
                              void* d_out, int out_size, void* d_ws, size_t ws_size,
                              hipStream_t stream) {
  const float* x   = (const float*)d_in[0];
  const float* Wq  = (const float*)d_in[1];
  const float* Wk  = (const float*)d_in[2];
  const float* Wv  = (const float*)d_in[3];
  const float* Wo  = (const float*)d_in[4];
  const float* bo  = (const float*)d_in[5];
  const float* W1  = (const float*)d_in[6];
  const float* b1  = (const float*)d_in[7];
  const float* W2  = (const float*)d_in[8];
  const float* b2  = (const float*)d_in[9];
  const float* g1  = (const float*)d_in[10];
  const float* be1 = (const float*)d_in[11];
  const float* g2  = (const float*)d_in[12];
  const float* be2 = (const float*)d_in[13];
  float* out = (float*)d_out;

  bf16* Wqkv_t = (bf16*)d_ws;                                  // [3][1024][1024]
  bf16* Wo_t   = Wqkv_t + (size_t)3 * D_MODEL * D_MODEL;       // [1024][1024]
  bf16* W1_t   = Wo_t + (size_t)D_MODEL * D_MODEL;             // [4096][1024]
  bf16* W2_t   = W1_t + (size_t)FFD * D_MODEL;                 // [1024][4096]
  bf16* hbuf   = W2_t + (size_t)D_MODEL * FFD;                 // [8192][1024] (h, later h2)
  float* x1    = (float*)(hbuf + (size_t)ROWS * D_MODEL);      // [8192][1024] fp32
  bf16* big    = (bf16*)(x1 + (size_t)ROWS * D_MODEL);         // qkv (50MB) then ff (64MB)
  bf16* qbuf   = big;
  bf16* kbuf   = qbuf + (size_t)ROWS * D_MODEL;
  bf16* vtbuf  = kbuf + (size_t)ROWS * D_MODEL;
  bf16* ffbuf  = big;                                          // reuse after attention
  bf16* attb   = big + (size_t)ROWS * FFD;                     // [8192][1024]

  qkv_transpose_kernel<<<dim3(D_MODEL / 32, HEAD / 32, 3 * N_HEAD), 256, 0, stream>>>(Wq, Wk, Wv, Wqkv_t);
  transpose_cast_kernel<<<dim3(D_MODEL / 32, D_MODEL / 32), 256, 0, stream>>>(Wo, Wo_t, D_MODEL, D_MODEL);
  transpose_cast_kernel<<<dim3(FFD / 32, D_MODEL / 32), 256, 0, stream>>>(W1, W1_t, D_MODEL, FFD);
  transpose_cast_kernel<<<dim3(D_MODEL / 32, FFD / 32), 256, 0, stream>>>(W2, W2_t, FFD, D_MODEL);
  ln_kernel<<<ROWS, 256, 0, stream>>>(x, g1, be1, hbuf);
  // grids: (M/BM)*(N/256), 1D, all %8==0; exact CU rounds: 768=3x256, 256, 512=2x256, 256
  gemm_qkv_kernel<<<dim3((3 * D_MODEL / 256) * (ROWS / 128)), 512, 0, stream>>>(
      hbuf, Wqkv_t, qbuf, kbuf, vtbuf);
  attn_kernel<<<64 * (SEQ / 256), 256, 0, stream>>>(qbuf, kbuf, vtbuf, attb);
  gemm_proj_kernel<<<dim3((D_MODEL / 256) * (ROWS / 128)), 512, 0, stream>>>(
      attb, Wo_t, x1, bo, x);
  ln_kernel<<<ROWS, 256, 0, stream>>>(x1, g2, be2, hbuf);
  gemm_ff1_kernel<<<dim3((FFD / 256) * (ROWS / 256)), 512, 0, stream>>>(
      hbuf, W1_t, ffbuf, b1);
  gemm_ff2_kernel<<<dim3((D_MODEL / 256) * (ROWS / 128)), 512, 0, stream>>>(
      ffbuf, W2_t, out, b2, x1);
}